// Round 1
// baseline (498.235 us; speedup 1.0000x reference)
//
#include <hip/hip_runtime.h>
#include <stdint.h>

// ---------------- JAX threefry2x32 (partitionable mode) ----------------
__host__ __device__ inline void tf2x32(uint32_t k0, uint32_t k1,
                                       uint32_t x0, uint32_t x1,
                                       uint32_t& o0, uint32_t& o1) {
  const uint32_t ks2 = k0 ^ k1 ^ 0x1BD11BDAu;
  x0 += k0; x1 += k1;
#define TFR(r) { x0 += x1; x1 = (x1 << (r)) | (x1 >> (32 - (r))); x1 ^= x0; }
  TFR(13) TFR(15) TFR(26) TFR(6)
  x0 += k1;  x1 += ks2 + 1u;
  TFR(17) TFR(29) TFR(16) TFR(24)
  x0 += ks2; x1 += k0 + 2u;
  TFR(13) TFR(15) TFR(26) TFR(6)
  x0 += k0;  x1 += k1 + 3u;
  TFR(17) TFR(29) TFR(16) TFR(24)
  x0 += k1;  x1 += ks2 + 4u;
  TFR(13) TFR(15) TFR(26) TFR(6)
  x0 += ks2; x1 += k0 + 5u;
#undef TFR
  o0 = x0; o1 = x1;
}

// 32-bit random bits, JAX partitionable threefry: counter = 64-bit flat index
// (hi=0 for our sizes), output = x0out ^ x1out.
__host__ __device__ inline uint32_t bits32(uint32_t k0, uint32_t k1, uint32_t idx) {
  uint32_t a, b;
  tf2x32(k0, k1, 0u, idx, a, b);
  return a ^ b;
}

// keep-edge iff uniform >= 0.5 iff bit31 of bits set (floor(0.5+u) == 1)
__device__ inline bool edge_kept(uint32_t k0, uint32_t k1, uint32_t e) {
  return (bits32(k0, k1, e) >> 31) != 0u;
}

// ---------------- CSR build ----------------
__global__ void k_count(const int* __restrict__ rows, int nnz, int* __restrict__ cnt,
                        uint32_t ke0, uint32_t ke1) {
  int e = blockIdx.x * 256 + threadIdx.x;
  if (e >= nnz) return;
  if (edge_kept(ke0, ke1, (uint32_t)e)) atomicAdd(&cnt[rows[e]], 1);
}

__global__ void k_blocksum(const int* __restrict__ cnt, int n, int* __restrict__ bsum) {
  __shared__ int s[256];
  int i = blockIdx.x * 256 + threadIdx.x;
  s[threadIdx.x] = (i < n) ? cnt[i] : 0;
  __syncthreads();
  for (int off = 128; off > 0; off >>= 1) {
    if (threadIdx.x < off) s[threadIdx.x] += s[threadIdx.x + off];
    __syncthreads();
  }
  if (threadIdx.x == 0) bsum[blockIdx.x] = s[0];
}

// single block, 1024 threads, scans up to 2048 block sums -> exclusive prefix
__global__ void k_scanb(const int* __restrict__ bsum, int nb, int* __restrict__ bpref) {
  __shared__ int a[2048], b[2048];
  int t = threadIdx.x;
  for (int i = t; i < 2048; i += 1024) a[i] = (i < nb) ? bsum[i] : 0;
  __syncthreads();
  int* cur = a; int* nxt = b;
  for (int off = 1; off < 2048; off <<= 1) {
    for (int i = t; i < 2048; i += 1024)
      nxt[i] = cur[i] + (i >= off ? cur[i - off] : 0);
    __syncthreads();
    int* tmp = cur; cur = nxt; nxt = tmp;
  }
  for (int i = t; i <= nb; i += 1024)
    bpref[i] = (i == 0) ? 0 : cur[i - 1];
}

__global__ void k_scan_write(const int* __restrict__ cnt, int n, const int* __restrict__ bpref,
                             int* __restrict__ row_ptr, int* __restrict__ nextc) {
  __shared__ int a[256], b[256];
  int t = threadIdx.x;
  int i = blockIdx.x * 256 + t;
  int v = (i < n) ? cnt[i] : 0;
  a[t] = v;
  __syncthreads();
  int* cur = a; int* nxt = b;
  for (int off = 1; off < 256; off <<= 1) {
    nxt[t] = cur[t] + (t >= off ? cur[t - off] : 0);
    __syncthreads();
    int* tmp = cur; cur = nxt; nxt = tmp;
  }
  int incl = cur[t] + bpref[blockIdx.x];
  int excl = incl - v;
  if (i < n) { row_ptr[i] = excl; nextc[i] = excl; }
  if (i == n - 1) row_ptr[n] = incl;
}

__global__ void k_scatter(const float* __restrict__ avals, const int* __restrict__ rows,
                          const int* __restrict__ cols, int nnz, int* __restrict__ nextc,
                          int* __restrict__ slot_col, float* __restrict__ slot_val,
                          uint32_t ke0, uint32_t ke1) {
  int e = blockIdx.x * 256 + threadIdx.x;
  if (e >= nnz) return;
  if (!edge_kept(ke0, ke1, (uint32_t)e)) return;
  int r = rows[e];
  int k = atomicAdd(&nextc[r], 1);
  slot_col[k] = cols[e];
  slot_val[k] = avals[e] * 2.0f;   // * keep * 1/(1-0.5), exact
}

// ---------------- SPMM: one wave per row, lane = dim ----------------
template <int FIRST>
__global__ __launch_bounds__(256) void k_spmm(
    const int* __restrict__ row_ptr, const int* __restrict__ slot_col,
    const float* __restrict__ slot_val, const float* __restrict__ xin,
    const float* __restrict__ uemb, const float* __restrict__ iemb,
    float* __restrict__ xout, int n_nodes, int nu) {
  int r = blockIdx.x * 4 + (threadIdx.x >> 6);
  if (r >= n_nodes) return;
  int lane = threadIdx.x & 63;
  int s = row_ptr[r], e = row_ptr[r + 1];
  float acc = 0.0f;
  for (int k = s; k < e; ++k) {
    int c = slot_col[k];
    float v = slot_val[k];
    float xv;
    if (FIRST) {
      xv = (c < nu) ? uemb[(size_t)c * 64 + lane]
                    : iemb[(size_t)(c - nu) * 64 + lane];
    } else {
      xv = xin[(size_t)c * 64 + lane];
    }
    acc += v * xv;
  }
  xout[(size_t)r * 64 + lane] = acc;
}

// ---------------- batch gather, accumulated into d_out ----------------
// out layout: [u_online | u_target | i_online | i_target], H = B*64 each.
// online slots hold the running acc sum until finalize.
template <int INIT>
__global__ void k_gather(const float* __restrict__ x, const float* __restrict__ uemb,
                         const float* __restrict__ iemb, const int* __restrict__ users,
                         const int* __restrict__ items, float* __restrict__ out,
                         int batch, int nu) {
  int b = blockIdx.x * 4 + (threadIdx.x >> 6);
  if (b >= 2 * batch) return;
  int lane = threadIdx.x & 63;
  size_t H = (size_t)batch * 64;
  float v;
  size_t dst;
  if (b < batch) {
    int row = users[b];
    dst = (size_t)b * 64 + lane;
    v = INIT ? uemb[(size_t)row * 64 + lane] : x[(size_t)row * 64 + lane];
  } else {
    int bi = b - batch;
    int row = items[bi];
    dst = 2 * H + (size_t)bi * 64 + lane;
    v = INIT ? iemb[(size_t)row * 64 + lane] : x[(size_t)(nu + row) * 64 + lane];
  }
  if (INIT) out[dst] = v;
  else out[dst] += v;
}

// ---------------- finalize: /4, target dropout masks ----------------
__global__ void k_finalize(float* __restrict__ out, int batch,
                           uint32_t ku0, uint32_t ku1, uint32_t ki0, uint32_t ki1) {
  int j = blockIdx.x * 256 + threadIdx.x;
  int H = batch * 64;
  if (j >= 2 * H) return;
  bool is_u = j < H;
  int f = is_u ? j : j - H;
  size_t online = is_u ? (size_t)f : (size_t)2 * H + f;
  uint32_t k0 = is_u ? ku0 : ki0;
  uint32_t k1 = is_u ? ku1 : ki1;
  float o = out[online] * 0.25f;                       // acc / (N_LAYERS+1), exact
  bool present = (bits32(k0, k1, (uint32_t)f) >> 31) == 0u;  // bernoulli(0.5): u < 0.5
  out[online] = o;
  out[online + H] = present ? o * 2.0f : 0.0f;         // t / (1-0.5), exact
}

extern "C" void kernel_launch(void* const* d_in, const int* in_sizes, int n_in,
                              void* d_out, int out_size, void* d_ws, size_t ws_size,
                              hipStream_t stream) {
  const float* uemb  = (const float*)d_in[0];
  const float* iemb  = (const float*)d_in[1];
  const float* avals = (const float*)d_in[2];
  const int*   rows  = (const int*)d_in[3];
  const int*   cols  = (const int*)d_in[4];
  const int*   users = (const int*)d_in[5];
  const int*   items = (const int*)d_in[6];
  const int DIM = 64;
  const int NU = in_sizes[0] / DIM;
  const int NI = in_sizes[1] / DIM;
  const int NNZ = in_sizes[2];
  const int B = in_sizes[5];
  const int NN = NU + NI;
  float* out = (float*)d_out;
  (void)n_in; (void)out_size; (void)ws_size;

  // derived subkeys: split(key(1234), 3) fold-like = threefry(key, (0, i))
  uint32_t ke0, ke1, ku0, ku1, ki0, ki1;
  tf2x32(0u, 1234u, 0u, 0u, ke0, ke1);
  tf2x32(0u, 1234u, 0u, 1u, ku0, ku1);
  tf2x32(0u, 1234u, 0u, 2u, ki0, ki1);

  // workspace carve (~172 MB)
  char* p = (char*)d_ws;
  auto carve = [&](size_t bytes) {
    char* r = p;
    p += (bytes + 255) & ~(size_t)255;
    return (void*)r;
  };
  float* X0       = (float*)carve((size_t)NN * DIM * 4);
  float* X1       = (float*)carve((size_t)NN * DIM * 4);
  int*   slot_col = (int*)carve((size_t)NNZ * 4);
  float* slot_val = (float*)carve((size_t)NNZ * 4);
  int*   cnt      = (int*)carve((size_t)NN * 4);
  int*   row_ptr  = (int*)carve((size_t)(NN + 1) * 4);
  int*   nextc    = (int*)carve((size_t)NN * 4);
  const int NB    = (NN + 255) / 256;
  int*   bsum     = (int*)carve((size_t)NB * 4);
  int*   bpref    = (int*)carve((size_t)(NB + 1) * 4);

  hipMemsetAsync(cnt, 0, (size_t)NN * 4, stream);

  const int gE = (NNZ + 255) / 256;
  k_count<<<gE, 256, 0, stream>>>(rows, NNZ, cnt, ke0, ke1);
  k_blocksum<<<NB, 256, 0, stream>>>(cnt, NN, bsum);
  k_scanb<<<1, 1024, 0, stream>>>(bsum, NB, bpref);
  k_scan_write<<<NB, 256, 0, stream>>>(cnt, NN, bpref, row_ptr, nextc);
  k_scatter<<<gE, 256, 0, stream>>>(avals, rows, cols, NNZ, nextc, slot_col, slot_val, ke0, ke1);

  const int gG = (2 * B + 3) / 4;
  const int gS = (NN + 3) / 4;

  // layer-0 contribution (the raw embeddings) into online slots
  k_gather<1><<<gG, 256, 0, stream>>>(X0, uemb, iemb, users, items, out, B, NU);

  // layer 1..3 with gather-accumulate after each
  k_spmm<1><<<gS, 256, 0, stream>>>(row_ptr, slot_col, slot_val, X1, uemb, iemb, X0, NN, NU);
  k_gather<0><<<gG, 256, 0, stream>>>(X0, uemb, iemb, users, items, out, B, NU);
  k_spmm<0><<<gS, 256, 0, stream>>>(row_ptr, slot_col, slot_val, X0, uemb, iemb, X1, NN, NU);
  k_gather<0><<<gG, 256, 0, stream>>>(X1, uemb, iemb, users, items, out, B, NU);
  k_spmm<0><<<gS, 256, 0, stream>>>(row_ptr, slot_col, slot_val, X1, uemb, iemb, X0, NN, NU);
  k_gather<0><<<gG, 256, 0, stream>>>(X0, uemb, iemb, users, items, out, B, NU);

  const int gF = (2 * B * DIM + 255) / 256;
  k_finalize<<<gF, 256, 0, stream>>>(out, B, ku0, ku1, ki0, ki1);
}

// Round 2
// 288.377 us; speedup vs baseline: 1.7277x; 1.7277x over previous
//
#include <hip/hip_runtime.h>
#include <stdint.h>

// ---------------- JAX threefry2x32 (partitionable mode) ----------------
__host__ __device__ inline void tf2x32(uint32_t k0, uint32_t k1,
                                       uint32_t x0, uint32_t x1,
                                       uint32_t& o0, uint32_t& o1) {
  const uint32_t ks2 = k0 ^ k1 ^ 0x1BD11BDAu;
  x0 += k0; x1 += k1;
#define TFR(r) { x0 += x1; x1 = (x1 << (r)) | (x1 >> (32 - (r))); x1 ^= x0; }
  TFR(13) TFR(15) TFR(26) TFR(6)
  x0 += k1;  x1 += ks2 + 1u;
  TFR(17) TFR(29) TFR(16) TFR(24)
  x0 += ks2; x1 += k0 + 2u;
  TFR(13) TFR(15) TFR(26) TFR(6)
  x0 += k0;  x1 += k1 + 3u;
  TFR(17) TFR(29) TFR(16) TFR(24)
  x0 += k1;  x1 += ks2 + 4u;
  TFR(13) TFR(15) TFR(26) TFR(6)
  x0 += ks2; x1 += k0 + 5u;
#undef TFR
  o0 = x0; o1 = x1;
}

__host__ __device__ inline uint32_t bits32(uint32_t k0, uint32_t k1, uint32_t idx) {
  uint32_t a, b;
  tf2x32(k0, k1, 0u, idx, a, b);
  return a ^ b;
}

// keep-edge iff uniform >= 0.5 iff bit31 of bits set (floor(0.5+u) == 1)
__device__ inline bool edge_kept(uint32_t k0, uint32_t k1, uint32_t e) {
  return (bits32(k0, k1, e) >> 31) != 0u;
}

// ---------------- CSR build ----------------
__global__ void k_count(const int* __restrict__ rows, int nnz, int* __restrict__ cnt,
                        uint32_t ke0, uint32_t ke1) {
  int e = blockIdx.x * 256 + threadIdx.x;
  if (e >= nnz) return;
  if (edge_kept(ke0, ke1, (uint32_t)e)) atomicAdd(&cnt[rows[e]], 1);
}

__global__ void k_blocksum(const int* __restrict__ cnt, int n, int* __restrict__ bsum) {
  __shared__ int s[256];
  int i = blockIdx.x * 256 + threadIdx.x;
  s[threadIdx.x] = (i < n) ? cnt[i] : 0;
  __syncthreads();
  for (int off = 128; off > 0; off >>= 1) {
    if (threadIdx.x < off) s[threadIdx.x] += s[threadIdx.x + off];
    __syncthreads();
  }
  if (threadIdx.x == 0) bsum[blockIdx.x] = s[0];
}

// single block, 1024 threads, scans up to 2048 block sums -> exclusive prefix
__global__ void k_scanb(const int* __restrict__ bsum, int nb, int* __restrict__ bpref) {
  __shared__ int a[2048], b[2048];
  int t = threadIdx.x;
  for (int i = t; i < 2048; i += 1024) a[i] = (i < nb) ? bsum[i] : 0;
  __syncthreads();
  int* cur = a; int* nxt = b;
  for (int off = 1; off < 2048; off <<= 1) {
    for (int i = t; i < 2048; i += 1024)
      nxt[i] = cur[i] + (i >= off ? cur[i - off] : 0);
    __syncthreads();
    int* tmp = cur; cur = nxt; nxt = tmp;
  }
  for (int i = t; i <= nb; i += 1024)
    bpref[i] = (i == 0) ? 0 : cur[i - 1];
}

__global__ void k_scan_write(const int* __restrict__ cnt, int n, const int* __restrict__ bpref,
                             int* __restrict__ row_ptr, int* __restrict__ nextc) {
  __shared__ int a[256], b[256];
  int t = threadIdx.x;
  int i = blockIdx.x * 256 + t;
  int v = (i < n) ? cnt[i] : 0;
  a[t] = v;
  __syncthreads();
  int* cur = a; int* nxt = b;
  for (int off = 1; off < 256; off <<= 1) {
    nxt[t] = cur[t] + (t >= off ? cur[t - off] : 0);
    __syncthreads();
    int* tmp = cur; cur = nxt; nxt = tmp;
  }
  int incl = cur[t] + bpref[blockIdx.x];
  int excl = incl - v;
  if (i < n) { row_ptr[i] = excl; nextc[i] = excl; }
  if (i == n - 1) row_ptr[n] = incl;
}

__global__ void k_scatter(const float* __restrict__ avals, const int* __restrict__ rows,
                          const int* __restrict__ cols, int nnz, int* __restrict__ nextc,
                          int2* __restrict__ slot, uint32_t ke0, uint32_t ke1) {
  int e = blockIdx.x * 256 + threadIdx.x;
  if (e >= nnz) return;
  if (!edge_kept(ke0, ke1, (uint32_t)e)) return;
  int r = rows[e];
  int k = atomicAdd(&nextc[r], 1);
  slot[k] = make_int2(cols[e], __float_as_int(avals[e] * 2.0f)); // *keep*1/(1-0.5)
}

// ---------------- SPMM: one wave per row, lane = dim, 4-wide edge MLP -------
template <int FIRST>
__device__ inline float ldx(int c, const float* __restrict__ xin,
                            const float* __restrict__ uemb,
                            const float* __restrict__ iemb, int nu, int lane) {
  if (FIRST) {
    const float* p = (c < nu) ? (uemb + (size_t)c * 64)
                              : (iemb + (size_t)(c - nu) * 64);
    return p[lane];
  }
  return xin[(size_t)c * 64 + lane];
}

template <int FIRST>
__global__ __launch_bounds__(256) void k_spmm(
    const int* __restrict__ row_ptr, const int2* __restrict__ slot,
    const float* __restrict__ xin, const float* __restrict__ uemb,
    const float* __restrict__ iemb, float* __restrict__ xout,
    int n_nodes, int nu) {
  int r = blockIdx.x * 4 + (threadIdx.x >> 6);
  if (r >= n_nodes) return;
  int lane = threadIdx.x & 63;
  int s = row_ptr[r], e = row_ptr[r + 1];
  float acc = 0.0f;
  int last = e - 1;
  for (int k = s; k < e; k += 4) {
    // 4 independent slot loads (clamped), then 4 independent x gathers
    int2 a0 = slot[k];
    int2 a1 = slot[(k + 1 < e) ? k + 1 : last];
    int2 a2 = slot[(k + 2 < e) ? k + 2 : last];
    int2 a3 = slot[(k + 3 < e) ? k + 3 : last];
    float v0 = __int_as_float(a0.y);
    float v1 = (k + 1 < e) ? __int_as_float(a1.y) : 0.0f;
    float v2 = (k + 2 < e) ? __int_as_float(a2.y) : 0.0f;
    float v3 = (k + 3 < e) ? __int_as_float(a3.y) : 0.0f;
    float x0 = ldx<FIRST>(a0.x, xin, uemb, iemb, nu, lane);
    float x1 = ldx<FIRST>(a1.x, xin, uemb, iemb, nu, lane);
    float x2 = ldx<FIRST>(a2.x, xin, uemb, iemb, nu, lane);
    float x3 = ldx<FIRST>(a3.x, xin, uemb, iemb, nu, lane);
    acc = fmaf(v0, x0, acc);
    acc = fmaf(v1, x1, acc);
    acc = fmaf(v2, x2, acc);
    acc = fmaf(v3, x3, acc);
  }
  xout[(size_t)r * 64 + lane] = acc;
}

// ---- layer-3 SPMM fused into the batch gather: only 2B rows are needed ----
__global__ __launch_bounds__(256) void k_spmm_gather(
    const int* __restrict__ row_ptr, const int2* __restrict__ slot,
    const float* __restrict__ xin, const int* __restrict__ users,
    const int* __restrict__ items, float* __restrict__ out,
    int batch, int nu) {
  int b = blockIdx.x * 4 + (threadIdx.x >> 6);
  if (b >= 2 * batch) return;
  int lane = threadIdx.x & 63;
  size_t H = (size_t)batch * 64;
  int r; size_t dst;
  if (b < batch) {
    r = users[b];
    dst = (size_t)b * 64 + lane;
  } else {
    int bi = b - batch;
    r = nu + items[bi];
    dst = 2 * H + (size_t)bi * 64 + lane;
  }
  int s = row_ptr[r], e = row_ptr[r + 1];
  float acc = 0.0f;
  int last = e - 1;
  for (int k = s; k < e; k += 4) {
    int2 a0 = slot[k];
    int2 a1 = slot[(k + 1 < e) ? k + 1 : last];
    int2 a2 = slot[(k + 2 < e) ? k + 2 : last];
    int2 a3 = slot[(k + 3 < e) ? k + 3 : last];
    float v0 = __int_as_float(a0.y);
    float v1 = (k + 1 < e) ? __int_as_float(a1.y) : 0.0f;
    float v2 = (k + 2 < e) ? __int_as_float(a2.y) : 0.0f;
    float v3 = (k + 3 < e) ? __int_as_float(a3.y) : 0.0f;
    float x0 = xin[(size_t)a0.x * 64 + lane];
    float x1 = xin[(size_t)a1.x * 64 + lane];
    float x2 = xin[(size_t)a2.x * 64 + lane];
    float x3 = xin[(size_t)a3.x * 64 + lane];
    acc = fmaf(v0, x0, acc);
    acc = fmaf(v1, x1, acc);
    acc = fmaf(v2, x2, acc);
    acc = fmaf(v3, x3, acc);
  }
  out[dst] += acc;
}

// ---------------- batch gather, accumulated into d_out ----------------
// out layout: [u_online | u_target | i_online | i_target], H = B*64 each.
template <int INIT>
__global__ void k_gather(const float* __restrict__ x, const float* __restrict__ uemb,
                         const float* __restrict__ iemb, const int* __restrict__ users,
                         const int* __restrict__ items, float* __restrict__ out,
                         int batch, int nu) {
  int b = blockIdx.x * 4 + (threadIdx.x >> 6);
  if (b >= 2 * batch) return;
  int lane = threadIdx.x & 63;
  size_t H = (size_t)batch * 64;
  float v;
  size_t dst;
  if (b < batch) {
    int row = users[b];
    dst = (size_t)b * 64 + lane;
    v = INIT ? uemb[(size_t)row * 64 + lane] : x[(size_t)row * 64 + lane];
  } else {
    int bi = b - batch;
    int row = items[bi];
    dst = 2 * H + (size_t)bi * 64 + lane;
    v = INIT ? iemb[(size_t)row * 64 + lane] : x[(size_t)(nu + row) * 64 + lane];
  }
  if (INIT) out[dst] = v;
  else out[dst] += v;
}

// ---------------- finalize: /4, target dropout masks ----------------
__global__ void k_finalize(float* __restrict__ out, int batch,
                           uint32_t ku0, uint32_t ku1, uint32_t ki0, uint32_t ki1) {
  int j = blockIdx.x * 256 + threadIdx.x;
  int H = batch * 64;
  if (j >= 2 * H) return;
  bool is_u = j < H;
  int f = is_u ? j : j - H;
  size_t online = is_u ? (size_t)f : (size_t)2 * H + f;
  uint32_t k0 = is_u ? ku0 : ki0;
  uint32_t k1 = is_u ? ku1 : ki1;
  float o = out[online] * 0.25f;                       // acc / (N_LAYERS+1), exact
  bool present = (bits32(k0, k1, (uint32_t)f) >> 31) == 0u;  // bernoulli(0.5)
  out[online] = o;
  out[online + H] = present ? o * 2.0f : 0.0f;         // t / (1-0.5), exact
}

extern "C" void kernel_launch(void* const* d_in, const int* in_sizes, int n_in,
                              void* d_out, int out_size, void* d_ws, size_t ws_size,
                              hipStream_t stream) {
  const float* uemb  = (const float*)d_in[0];
  const float* iemb  = (const float*)d_in[1];
  const float* avals = (const float*)d_in[2];
  const int*   rows  = (const int*)d_in[3];
  const int*   cols  = (const int*)d_in[4];
  const int*   users = (const int*)d_in[5];
  const int*   items = (const int*)d_in[6];
  const int DIM = 64;
  const int NU = in_sizes[0] / DIM;
  const int NI = in_sizes[1] / DIM;
  const int NNZ = in_sizes[2];
  const int B = in_sizes[5];
  const int NN = NU + NI;
  float* out = (float*)d_out;
  (void)n_in; (void)out_size; (void)ws_size;

  // derived subkeys: split(key(1234), 3) fold-like = threefry(key, (0, i))
  uint32_t ke0, ke1, ku0, ku1, ki0, ki1;
  tf2x32(0u, 1234u, 0u, 0u, ke0, ke1);
  tf2x32(0u, 1234u, 0u, 1u, ku0, ku1);
  tf2x32(0u, 1234u, 0u, 2u, ki0, ki1);

  // workspace carve
  char* p = (char*)d_ws;
  auto carve = [&](size_t bytes) {
    char* r = p;
    p += (bytes + 255) & ~(size_t)255;
    return (void*)r;
  };
  float* X0       = (float*)carve((size_t)NN * DIM * 4);
  float* X1       = (float*)carve((size_t)NN * DIM * 4);
  int2*  slot     = (int2*)carve((size_t)NNZ * 8);
  int*   cnt      = (int*)carve((size_t)NN * 4);
  int*   row_ptr  = (int*)carve((size_t)(NN + 1) * 4);
  int*   nextc    = (int*)carve((size_t)NN * 4);
  const int NB    = (NN + 255) / 256;
  int*   bsum     = (int*)carve((size_t)NB * 4);
  int*   bpref    = (int*)carve((size_t)(NB + 1) * 4);

  hipMemsetAsync(cnt, 0, (size_t)NN * 4, stream);

  const int gE = (NNZ + 255) / 256;
  k_count<<<gE, 256, 0, stream>>>(rows, NNZ, cnt, ke0, ke1);
  k_blocksum<<<NB, 256, 0, stream>>>(cnt, NN, bsum);
  k_scanb<<<1, 1024, 0, stream>>>(bsum, NB, bpref);
  k_scan_write<<<NB, 256, 0, stream>>>(cnt, NN, bpref, row_ptr, nextc);
  k_scatter<<<gE, 256, 0, stream>>>(avals, rows, cols, NNZ, nextc, slot, ke0, ke1);

  const int gG = (2 * B + 3) / 4;
  const int gS = (NN + 3) / 4;

  // layer-0 contribution (the raw embeddings) into online slots
  k_gather<1><<<gG, 256, 0, stream>>>(X0, uemb, iemb, users, items, out, B, NU);

  // layer 1: X0 = A * emb, accumulate batch rows
  k_spmm<1><<<gS, 256, 0, stream>>>(row_ptr, slot, X1, uemb, iemb, X0, NN, NU);
  k_gather<0><<<gG, 256, 0, stream>>>(X0, uemb, iemb, users, items, out, B, NU);
  // layer 2: X1 = A * X0, accumulate batch rows
  k_spmm<0><<<gS, 256, 0, stream>>>(row_ptr, slot, X0, uemb, iemb, X1, NN, NU);
  k_gather<0><<<gG, 256, 0, stream>>>(X1, uemb, iemb, users, items, out, B, NU);
  // layer 3: only the 2B gathered rows are ever read -> fuse into gather
  k_spmm_gather<<<gG, 256, 0, stream>>>(row_ptr, slot, X1, users, items, out, B, NU);

  const int gF = (2 * B * DIM + 255) / 256;
  k_finalize<<<gF, 256, 0, stream>>>(out, B, ku0, ku1, ki0, ki1);
}

// Round 3
// 246.025 us; speedup vs baseline: 2.0251x; 1.1721x over previous
//
#include <hip/hip_runtime.h>
#include <stdint.h>

// ---------------- JAX threefry2x32 (partitionable mode) ----------------
__host__ __device__ inline void tf2x32(uint32_t k0, uint32_t k1,
                                       uint32_t x0, uint32_t x1,
                                       uint32_t& o0, uint32_t& o1) {
  const uint32_t ks2 = k0 ^ k1 ^ 0x1BD11BDAu;
  x0 += k0; x1 += k1;
#define TFR(r) { x0 += x1; x1 = (x1 << (r)) | (x1 >> (32 - (r))); x1 ^= x0; }
  TFR(13) TFR(15) TFR(26) TFR(6)
  x0 += k1;  x1 += ks2 + 1u;
  TFR(17) TFR(29) TFR(16) TFR(24)
  x0 += ks2; x1 += k0 + 2u;
  TFR(13) TFR(15) TFR(26) TFR(6)
  x0 += k0;  x1 += k1 + 3u;
  TFR(17) TFR(29) TFR(16) TFR(24)
  x0 += k1;  x1 += ks2 + 4u;
  TFR(13) TFR(15) TFR(26) TFR(6)
  x0 += ks2; x1 += k0 + 5u;
#undef TFR
  o0 = x0; o1 = x1;
}

__host__ __device__ inline uint32_t bits32(uint32_t k0, uint32_t k1, uint32_t idx) {
  uint32_t a, b;
  tf2x32(k0, k1, 0u, idx, a, b);
  return a ^ b;
}

// keep-edge iff uniform >= 0.5 iff bit31 of bits set (floor(0.5+u) == 1)
__device__ inline bool edge_kept(uint32_t k0, uint32_t k1, uint32_t e) {
  return (bits32(k0, k1, e) >> 31) != 0u;
}

__device__ inline float bf_lo(uint32_t u) { return __uint_as_float(u << 16); }
__device__ inline float bf_hi(uint32_t u) { return __uint_as_float(u & 0xffff0000u); }
__device__ inline uint32_t bf_pack(float a, float b) {
  uint32_t lo = (__float_as_uint(a) + 0x8000u) >> 16;
  uint32_t hi = (__float_as_uint(b) + 0x8000u) & 0xffff0000u;
  return hi | lo;
}

// ---------------- CSR build ----------------
__global__ void k_count(const int* __restrict__ rows, int nnz, int* __restrict__ cnt,
                        uint32_t ke0, uint32_t ke1) {
  int e = blockIdx.x * 256 + threadIdx.x;
  if (e >= nnz) return;
  if (edge_kept(ke0, ke1, (uint32_t)e)) atomicAdd(&cnt[rows[e]], 1);
}

__global__ void k_blocksum(const int* __restrict__ cnt, int n, int* __restrict__ bsum) {
  __shared__ int s[256];
  int i = blockIdx.x * 256 + threadIdx.x;
  s[threadIdx.x] = (i < n) ? cnt[i] : 0;
  __syncthreads();
  for (int off = 128; off > 0; off >>= 1) {
    if (threadIdx.x < off) s[threadIdx.x] += s[threadIdx.x + off];
    __syncthreads();
  }
  if (threadIdx.x == 0) bsum[blockIdx.x] = s[0];
}

// single block, 1024 threads, scans up to 2048 block sums -> exclusive prefix
__global__ void k_scanb(const int* __restrict__ bsum, int nb, int* __restrict__ bpref) {
  __shared__ int a[2048], b[2048];
  int t = threadIdx.x;
  for (int i = t; i < 2048; i += 1024) a[i] = (i < nb) ? bsum[i] : 0;
  __syncthreads();
  int* cur = a; int* nxt = b;
  for (int off = 1; off < 2048; off <<= 1) {
    for (int i = t; i < 2048; i += 1024)
      nxt[i] = cur[i] + (i >= off ? cur[i - off] : 0);
    __syncthreads();
    int* tmp = cur; cur = nxt; nxt = tmp;
  }
  for (int i = t; i <= nb; i += 1024)
    bpref[i] = (i == 0) ? 0 : cur[i - 1];
}

__global__ void k_scan_write(const int* __restrict__ cnt, int n, const int* __restrict__ bpref,
                             int* __restrict__ row_ptr, int* __restrict__ nextc) {
  __shared__ int a[256], b[256];
  int t = threadIdx.x;
  int i = blockIdx.x * 256 + t;
  int v = (i < n) ? cnt[i] : 0;
  a[t] = v;
  __syncthreads();
  int* cur = a; int* nxt = b;
  for (int off = 1; off < 256; off <<= 1) {
    nxt[t] = cur[t] + (t >= off ? cur[t - off] : 0);
    __syncthreads();
    int* tmp = cur; cur = nxt; nxt = tmp;
  }
  int incl = cur[t] + bpref[blockIdx.x];
  int excl = incl - v;
  if (i < n) { row_ptr[i] = excl; nextc[i] = excl; }
  if (i == n - 1) row_ptr[n] = incl;
}

__global__ void k_scatter(const float* __restrict__ avals, const int* __restrict__ rows,
                          const int* __restrict__ cols, int nnz, int* __restrict__ nextc,
                          int2* __restrict__ slot, uint32_t ke0, uint32_t ke1) {
  int e = blockIdx.x * 256 + threadIdx.x;
  if (e >= nnz) return;
  if (!edge_kept(ke0, ke1, (uint32_t)e)) return;
  int r = rows[e];
  int k = atomicAdd(&nextc[r], 1);
  slot[k] = make_int2(cols[e], __float_as_int(avals[e] * 2.0f)); // *keep*1/(1-0.5)
}

// ---------------- frontier marking ----------------
__global__ void k_mark_batch(const int* __restrict__ users, const int* __restrict__ items,
                             int batch, int nu, uint8_t* fB, uint8_t* f1, uint8_t* f2) {
  int i = blockIdx.x * 256 + threadIdx.x;
  if (i >= 2 * batch) return;
  int r = (i < batch) ? users[i] : nu + items[i - batch];
  fB[r] = 1; f1[r] = 1; f2[r] = 1;
}

__global__ void k_mark_neighbors(const uint8_t* __restrict__ fin,
                                 const int* __restrict__ row_ptr,
                                 const int2* __restrict__ slot, int n,
                                 uint8_t* __restrict__ fout) {
  int r = blockIdx.x * 256 + threadIdx.x;
  if (r >= n) return;
  if (!fin[r]) return;
  int s = row_ptr[r], e = row_ptr[r + 1];
  for (int k = s; k < e; ++k) fout[slot[k].x] = 1;
}

// -------- SPMM: wave per row, 32 lanes = dim pairs, halves = edge pairs -----
// X buffers are bf16x2-packed (uint32, 32 words per row).
template <int FIRST>
__global__ __launch_bounds__(256) void k_spmm(
    const int* __restrict__ row_ptr, const int2* __restrict__ slot,
    const uint32_t* __restrict__ xin, const float* __restrict__ uemb,
    const float* __restrict__ iemb, uint32_t* __restrict__ xout,
    const uint8_t* __restrict__ flag, int n_nodes, int nu) {
  int r = blockIdx.x * 4 + (threadIdx.x >> 6);
  if (r >= n_nodes) return;
  if (!flag[r]) return;
  int lane = threadIdx.x & 63;
  int h = lane >> 5;   // which edge of a pair
  int m = lane & 31;   // dim pair index
  int s = row_ptr[r], e = row_ptr[r + 1];
  float a0 = 0.0f, a1 = 0.0f;
  int last = e - 1;
  for (int k = s; k < e; k += 4) {
    int i0 = k + h, i1 = k + 2 + h;
    int2 s0 = slot[(i0 <= last) ? i0 : last];
    int2 s1 = slot[(i1 <= last) ? i1 : last];
    float v0 = (i0 <= last) ? __int_as_float(s0.y) : 0.0f;
    float v1 = (i1 <= last) ? __int_as_float(s1.y) : 0.0f;
    if (FIRST) {
      const float* p0 = (s0.x < nu) ? uemb + (size_t)s0.x * 64
                                    : iemb + (size_t)(s0.x - nu) * 64;
      const float* p1 = (s1.x < nu) ? uemb + (size_t)s1.x * 64
                                    : iemb + (size_t)(s1.x - nu) * 64;
      float2 x0 = *(const float2*)(p0 + 2 * m);
      float2 x1 = *(const float2*)(p1 + 2 * m);
      a0 = fmaf(v0, x0.x, a0); a1 = fmaf(v0, x0.y, a1);
      a0 = fmaf(v1, x1.x, a0); a1 = fmaf(v1, x1.y, a1);
    } else {
      uint32_t u0 = xin[(size_t)s0.x * 32 + m];
      uint32_t u1 = xin[(size_t)s1.x * 32 + m];
      a0 = fmaf(v0, bf_lo(u0), a0); a1 = fmaf(v0, bf_hi(u0), a1);
      a0 = fmaf(v1, bf_lo(u1), a0); a1 = fmaf(v1, bf_hi(u1), a1);
    }
  }
  a0 += __shfl_xor(a0, 32, 64);
  a1 += __shfl_xor(a1, 32, 64);
  if (h == 0) xout[(size_t)r * 32 + m] = bf_pack(a0, a1);
}

// ---- layer-3 SPMM fused into the batch gather: only 2B rows are needed ----
__global__ __launch_bounds__(256) void k_spmm_gather(
    const int* __restrict__ row_ptr, const int2* __restrict__ slot,
    const uint32_t* __restrict__ xin, const int* __restrict__ users,
    const int* __restrict__ items, float* __restrict__ out,
    int batch, int nu) {
  int b = blockIdx.x * 4 + (threadIdx.x >> 6);
  if (b >= 2 * batch) return;
  int lane = threadIdx.x & 63;
  int h = lane >> 5, m = lane & 31;
  size_t H = (size_t)batch * 64;
  int r; size_t dst;
  if (b < batch) {
    r = users[b];
    dst = (size_t)b * 64;
  } else {
    int bi = b - batch;
    r = nu + items[bi];
    dst = 2 * H + (size_t)bi * 64;
  }
  int s = row_ptr[r], e = row_ptr[r + 1];
  float a0 = 0.0f, a1 = 0.0f;
  int last = e - 1;
  for (int k = s; k < e; k += 4) {
    int i0 = k + h, i1 = k + 2 + h;
    int2 s0 = slot[(i0 <= last) ? i0 : last];
    int2 s1 = slot[(i1 <= last) ? i1 : last];
    float v0 = (i0 <= last) ? __int_as_float(s0.y) : 0.0f;
    float v1 = (i1 <= last) ? __int_as_float(s1.y) : 0.0f;
    uint32_t u0 = xin[(size_t)s0.x * 32 + m];
    uint32_t u1 = xin[(size_t)s1.x * 32 + m];
    a0 = fmaf(v0, bf_lo(u0), a0); a1 = fmaf(v0, bf_hi(u0), a1);
    a0 = fmaf(v1, bf_lo(u1), a0); a1 = fmaf(v1, bf_hi(u1), a1);
  }
  a0 += __shfl_xor(a0, 32, 64);
  a1 += __shfl_xor(a1, 32, 64);
  if (h == 0) {
    float2* o = (float2*)(out + dst + 2 * m);
    float2 t = *o;
    t.x += a0; t.y += a1;
    *o = t;
  }
}

// ---------------- batch gather, accumulated into d_out ----------------
// out layout: [u_online | u_target | i_online | i_target], H = B*64 each.
template <int INIT>
__global__ void k_gather(const uint32_t* __restrict__ x, const float* __restrict__ uemb,
                         const float* __restrict__ iemb, const int* __restrict__ users,
                         const int* __restrict__ items, float* __restrict__ out,
                         int batch, int nu) {
  int b = blockIdx.x * 8 + (threadIdx.x >> 5);
  if (b >= 2 * batch) return;
  int m = threadIdx.x & 31;
  size_t H = (size_t)batch * 64;
  int row; size_t dst; bool isu = b < batch;
  if (isu) {
    row = users[b];
    dst = (size_t)b * 64 + 2 * m;
  } else {
    int bi = b - batch;
    row = items[bi];
    dst = 2 * H + (size_t)bi * 64 + 2 * m;
  }
  if (INIT) {
    const float* p = isu ? uemb + (size_t)row * 64 : iemb + (size_t)row * 64;
    *(float2*)(out + dst) = *(const float2*)(p + 2 * m);
  } else {
    int xr = isu ? row : nu + row;
    uint32_t u = x[(size_t)xr * 32 + m];
    float2* o = (float2*)(out + dst);
    float2 t = *o;
    t.x += bf_lo(u);
    t.y += bf_hi(u);
    *o = t;
  }
}

// ---------------- finalize: /4, target dropout masks ----------------
__global__ void k_finalize(float* __restrict__ out, int batch,
                           uint32_t ku0, uint32_t ku1, uint32_t ki0, uint32_t ki1) {
  int j = blockIdx.x * 256 + threadIdx.x;
  int H = batch * 64;
  if (j >= 2 * H) return;
  bool is_u = j < H;
  int f = is_u ? j : j - H;
  size_t online = is_u ? (size_t)f : (size_t)2 * H + f;
  uint32_t k0 = is_u ? ku0 : ki0;
  uint32_t k1 = is_u ? ku1 : ki1;
  float o = out[online] * 0.25f;                       // acc / (N_LAYERS+1), exact
  bool present = (bits32(k0, k1, (uint32_t)f) >> 31) == 0u;  // bernoulli(0.5)
  out[online] = o;
  out[online + H] = present ? o * 2.0f : 0.0f;         // t / (1-0.5), exact
}

extern "C" void kernel_launch(void* const* d_in, const int* in_sizes, int n_in,
                              void* d_out, int out_size, void* d_ws, size_t ws_size,
                              hipStream_t stream) {
  const float* uemb  = (const float*)d_in[0];
  const float* iemb  = (const float*)d_in[1];
  const float* avals = (const float*)d_in[2];
  const int*   rows  = (const int*)d_in[3];
  const int*   cols  = (const int*)d_in[4];
  const int*   users = (const int*)d_in[5];
  const int*   items = (const int*)d_in[6];
  const int DIM = 64;
  const int NU = in_sizes[0] / DIM;
  const int NI = in_sizes[1] / DIM;
  const int NNZ = in_sizes[2];
  const int B = in_sizes[5];
  const int NN = NU + NI;
  float* out = (float*)d_out;
  (void)n_in; (void)out_size; (void)ws_size;

  // derived subkeys: split(key(1234), 3) fold-like = threefry(key, (0, i))
  uint32_t ke0, ke1, ku0, ku1, ki0, ki1;
  tf2x32(0u, 1234u, 0u, 0u, ke0, ke1);
  tf2x32(0u, 1234u, 0u, 1u, ku0, ku1);
  tf2x32(0u, 1234u, 0u, 2u, ki0, ki1);

  // workspace carve
  char* p = (char*)d_ws;
  auto carve = [&](size_t bytes) {
    char* r = p;
    p += (bytes + 255) & ~(size_t)255;
    return (void*)r;
  };
  uint32_t* X0    = (uint32_t*)carve((size_t)NN * 32 * 4);  // bf16x2 rows
  uint32_t* X1    = (uint32_t*)carve((size_t)NN * 32 * 4);
  int2*  slot     = (int2*)carve((size_t)NNZ * 8);
  int*   cnt      = (int*)carve((size_t)NN * 4);
  int*   row_ptr  = (int*)carve((size_t)(NN + 1) * 4);
  int*   nextc    = (int*)carve((size_t)NN * 4);
  uint8_t* fB     = (uint8_t*)carve((size_t)NN);
  uint8_t* f1     = (uint8_t*)carve((size_t)NN);
  uint8_t* f2     = (uint8_t*)carve((size_t)NN);
  const int NB    = (NN + 255) / 256;
  int*   bsum     = (int*)carve((size_t)NB * 4);
  int*   bpref    = (int*)carve((size_t)(NB + 1) * 4);

  hipMemsetAsync(cnt, 0, (size_t)NN * 4, stream);
  hipMemsetAsync(fB, 0, (size_t)NN * 3, stream);  // fB, f1, f2 contiguous

  const int gE = (NNZ + 255) / 256;
  const int gN = (NN + 255) / 256;
  k_count<<<gE, 256, 0, stream>>>(rows, NNZ, cnt, ke0, ke1);
  k_blocksum<<<NB, 256, 0, stream>>>(cnt, NN, bsum);
  k_scanb<<<1, 1024, 0, stream>>>(bsum, NB, bpref);
  k_scan_write<<<NB, 256, 0, stream>>>(cnt, NN, bpref, row_ptr, nextc);
  k_scatter<<<gE, 256, 0, stream>>>(avals, rows, cols, NNZ, nextc, slot, ke0, ke1);

  // frontier: f2 = batch ∪ N(batch); f1 = batch ∪ N(f2)
  const int gB = (2 * B + 255) / 256;
  k_mark_batch<<<gB, 256, 0, stream>>>(users, items, B, NU, fB, f1, f2);
  k_mark_neighbors<<<gN, 256, 0, stream>>>(fB, row_ptr, slot, NN, f2);
  k_mark_neighbors<<<gN, 256, 0, stream>>>(f2, row_ptr, slot, NN, f1);

  const int gG = (2 * B + 7) / 8;     // k_gather: 8 rows/block
  const int gG4 = (2 * B + 3) / 4;    // spmm_gather: 4 rows/block
  const int gS = (NN + 3) / 4;

  // layer-0 contribution (the raw embeddings) into online slots
  k_gather<1><<<gG, 256, 0, stream>>>(X0, uemb, iemb, users, items, out, B, NU);

  // layer 1: X0 = A * emb (rows in f1), accumulate batch rows
  k_spmm<1><<<gS, 256, 0, stream>>>(row_ptr, slot, X1, uemb, iemb, X0, f1, NN, NU);
  k_gather<0><<<gG, 256, 0, stream>>>(X0, uemb, iemb, users, items, out, B, NU);
  // layer 2: X1 = A * X0 (rows in f2), accumulate batch rows
  k_spmm<0><<<gS, 256, 0, stream>>>(row_ptr, slot, X0, uemb, iemb, X1, f2, NN, NU);
  k_gather<0><<<gG, 256, 0, stream>>>(X1, uemb, iemb, users, items, out, B, NU);
  // layer 3: only the 2B gathered rows are ever read -> fuse into gather
  k_spmm_gather<<<gG4, 256, 0, stream>>>(row_ptr, slot, X1, users, items, out, B, NU);

  const int gF = (2 * B * DIM + 255) / 256;
  k_finalize<<<gF, 256, 0, stream>>>(out, B, ku0, ku1, ki0, ki1);
}